// Round 5
// baseline (403.166 us; speedup 1.0000x reference)
//
#include <hip/hip_runtime.h>
#include <hip/hip_bf16.h>
#include <cstdint>
#include <cstddef>

typedef short bf16x8 __attribute__((ext_vector_type(8)));
typedef float f32x4 __attribute__((ext_vector_type(4)));

__device__ __forceinline__ void gload_lds16(const void* g, void* l) {
  __builtin_amdgcn_global_load_lds((__attribute__((address_space(1))) const void*)g,
                                   (__attribute__((address_space(3))) void*)l, 16, 0, 0);
}

__device__ __forceinline__ unsigned short f2bf(float f) {
  unsigned u = __builtin_bit_cast(unsigned, f);
  u += 0x7fffu + ((u >> 16) & 1u);
  return (unsigned short)(u >> 16);
}
__device__ __forceinline__ float bf2f(unsigned short h) {
  unsigned u = ((unsigned)h) << 16;
  return __builtin_bit_cast(float, u);
}

// ---------------- cast f32 -> bf16 (vectorized) ----------------
__global__ void k_cast(const float* __restrict__ in, unsigned short* __restrict__ out, int n4) {
  int i = blockIdx.x * blockDim.x + threadIdx.x;
  int stride = gridDim.x * blockDim.x;
  for (; i < n4; i += stride) {
    float4 v = reinterpret_cast<const float4*>(in)[i];
    ushort4 o;
    o.x = f2bf(v.x); o.y = f2bf(v.y); o.z = f2bf(v.z); o.w = f2bf(v.w);
    reinterpret_cast<ushort4*>(out)[i] = o;
  }
}

__device__ __forceinline__ void storeC(float* C, size_t i, float v) { C[i] = v; }
__device__ __forceinline__ void storeC(unsigned short* C, size_t i, float v) { C[i] = f2bf(v); }

// ---------------- 128x128 GEMM (m97 structure) — small problems only -------
template <typename OutT>
__global__ __launch_bounds__(256) void k_gemm_bt(
    const unsigned short* __restrict__ A,
    const unsigned short* __restrict__ B,
    OutT* __restrict__ C,
    int M, int N, int K) {
  __shared__ __align__(16) unsigned short lA[128 * 64];
  __shared__ __align__(16) unsigned short lB[128 * 64];
  const int tid = threadIdx.x;
  const int w = tid >> 6, l = tid & 63;
  const int nwg = gridDim.x * gridDim.y;
  const int orig = blockIdx.y * gridDim.x + blockIdx.x;
  const int cpx = nwg >> 3;
  const int tile = (orig & 7) * cpx + (orig >> 3);
  const int m0 = (tile % gridDim.x) * 128;
  const int n0 = (tile / gridDim.x) * 128;
  const int wm = (w >> 1) * 64, wn = (w & 1) * 64;

  f32x4 acc[4][4];
#pragma unroll
  for (int i = 0; i < 4; ++i)
#pragma unroll
    for (int j = 0; j < 4; ++j) acc[i][j] = f32x4{0.f, 0.f, 0.f, 0.f};

  char* lAc = (char*)lA;
  char* lBc = (char*)lB;

  for (int k0 = 0; k0 < K; k0 += 64) {
#pragma unroll
    for (int p = 0; p < 4; ++p) {
      int r = (w * 4 + p) * 8 + (l >> 3);
      int c = (l & 7) ^ (r & 7);
      gload_lds16(A + (size_t)(m0 + r) * K + k0 + c * 8, lAc + (w * 4 + p) * 1024);
      gload_lds16(B + (size_t)(n0 + r) * K + k0 + c * 8, lBc + (w * 4 + p) * 1024);
    }
    __syncthreads();
#pragma unroll
    for (int kk = 0; kk < 2; ++kk) {
      bf16x8 af[4], bfr[4];
#pragma unroll
      for (int i = 0; i < 4; ++i) {
        int r = wm + i * 16 + (l & 15);
        int slot = (kk * 4 + (l >> 4)) ^ (r & 7);
        af[i] = *(const bf16x8*)(lAc + r * 128 + slot * 16);
      }
#pragma unroll
      for (int j = 0; j < 4; ++j) {
        int r = wn + j * 16 + (l & 15);
        int slot = (kk * 4 + (l >> 4)) ^ (r & 7);
        bfr[j] = *(const bf16x8*)(lBc + r * 128 + slot * 16);
      }
#pragma unroll
      for (int i = 0; i < 4; ++i)
#pragma unroll
        for (int j = 0; j < 4; ++j)
          acc[i][j] = __builtin_amdgcn_mfma_f32_16x16x32_bf16(af[i], bfr[j], acc[i][j], 0, 0, 0);
    }
    __syncthreads();
  }

#pragma unroll
  for (int i = 0; i < 4; ++i)
#pragma unroll
    for (int j = 0; j < 4; ++j) {
      int row = m0 + wm + i * 16 + (l >> 4) * 4;
      int col = n0 + wn + j * 16 + (l & 15);
#pragma unroll
      for (int r = 0; r < 4; ++r)
        storeC(C, (size_t)(row + r) * N + col, acc[i][j][r]);
    }
}

// ---------------- 256x256 8-phase GEMM (T2+T3+T4+T5) -----------------------
// Requires M % 256 == 0, M/256 == 8 blocks-in-m, N % 256 == 0, K % 64 == 0,
// K/64 >= 4. Grid = 1-D, 8*(N/256) blocks, 512 threads.
// LDS [buf][kk-half][256 rows][32 kcols], XOR chunk swizzle; per K-tile:
//   p1: read B-kk0 (regs) + A-kk0 lo ; stage (T+1) A-h1 -> other buf
//   p2: read A-kk0 hi               ; stage (T+2) B-h0 -> this buf (dead p1)
//   p3: read B-kk1 + A-kk1 lo       ; stage (T+2) A-h0 -> this buf (dead p2)
//   p4: read A-kk1 hi               ; stage (T+2) B-h1 -> this buf (dead p3)
// vmcnt(6) once per K-tile (3 half-tiles in flight across the barrier).
#define READ_B4(bf, kh)                                                        \
  {                                                                            \
    bfr[0] = *(const bf16x8*)&lB[bf][kh][wc * 64 + 0 * 16 + lq][fslot];        \
    bfr[1] = *(const bf16x8*)&lB[bf][kh][wc * 64 + 1 * 16 + lq][fslot];        \
    bfr[2] = *(const bf16x8*)&lB[bf][kh][wc * 64 + 2 * 16 + lq][fslot];        \
    bfr[3] = *(const bf16x8*)&lB[bf][kh][wc * 64 + 3 * 16 + lq][fslot];        \
  }
#define READ_A4(bf, kh, mfb)                                                   \
  {                                                                            \
    a[0] = *(const bf16x8*)&lA[bf][kh][wr * 128 + ((mfb) + 0) * 16 + lq][fslot];\
    a[1] = *(const bf16x8*)&lA[bf][kh][wr * 128 + ((mfb) + 1) * 16 + lq][fslot];\
    a[2] = *(const bf16x8*)&lA[bf][kh][wr * 128 + ((mfb) + 2) * 16 + lq][fslot];\
    a[3] = *(const bf16x8*)&lA[bf][kh][wr * 128 + ((mfb) + 3) * 16 + lq][fslot];\
  }
#define MFMA16(mfb)                                                            \
  _Pragma("unroll") for (int i = 0; i < 4; ++i)                                \
      _Pragma("unroll") for (int nf = 0; nf < 4; ++nf)                         \
          acc[(mfb) + i][nf] = __builtin_amdgcn_mfma_f32_16x16x32_bf16(        \
              a[i], bfr[nf], acc[(mfb) + i][nf], 0, 0, 0);
#define PHASE_SYNC_PRE()                         \
  __builtin_amdgcn_sched_barrier(0);             \
  __builtin_amdgcn_s_barrier();                  \
  asm volatile("s_waitcnt lgkmcnt(0)" ::: "memory"); \
  __builtin_amdgcn_sched_barrier(0);             \
  __builtin_amdgcn_s_setprio(1);
#define PHASE_SYNC_POST()                        \
  __builtin_amdgcn_s_setprio(0);                 \
  __builtin_amdgcn_sched_barrier(0);             \
  __builtin_amdgcn_s_barrier();                  \
  __builtin_amdgcn_sched_barrier(0);

template <typename OutT>
__global__ __launch_bounds__(512) void k_gemm256(
    const unsigned short* __restrict__ A,
    const unsigned short* __restrict__ B,
    OutT* __restrict__ C,
    int M, int N, int K) {
  __shared__ __align__(16) unsigned short lA[2][2][256][32];
  __shared__ __align__(16) unsigned short lB[2][2][256][32];
  const int tid = threadIdx.x;
  const int w = tid >> 6, l = tid & 63;
  const int wr = w >> 2, wc = w & 3;
  const int lq = l & 15, g = l >> 4;
  const int fslot = (g ^ ((lq >> 1) & 3)) << 3;  // element offset in 32-col row

  // XCD-aware 2-D partition: 8 m-blocks x gy n-blocks; each XCD owns 4m x gy/4 n.
  const int gy = (int)gridDim.x >> 3;
  const int L = (int)blockIdx.x;
  const int xcd = L & 7, slot = L >> 3;
  const int m0 = ((xcd >> 2) * 4 + (slot & 3)) * 256;
  const int n0 = ((xcd & 3) * (gy >> 2) + (slot >> 2)) * 256;

  const unsigned short* Ap = A + (size_t)m0 * K;
  const unsigned short* Bp = B + (size_t)n0 * K;

  f32x4 acc[8][4];
#pragma unroll
  for (int i = 0; i < 8; ++i)
#pragma unroll
    for (int j = 0; j < 4; ++j) acc[i][j] = f32x4{0.f, 0.f, 0.f, 0.f};

  // stage one half-tile (16 KB): this wave covers rows w*32 .. w*32+31
  auto stageHT = [&](const unsigned short* gbase, unsigned short* lbase, int kcol) {
#pragma unroll
    for (int p = 0; p < 2; ++p) {
      int R = w * 32 + p * 16;
      int row = R + (l >> 2);
      int cc = ((l & 3) ^ ((l >> 3) & 3)) << 3;
      gload_lds16(gbase + (size_t)row * K + kcol + cc, lbase + R * 32);
    }
  };

  const int nt = K >> 6;

  // prologue: T0 {Bh0,Ah0,Bh1,Ah1} -> buf0 ; T1 {Bh0,Ah0,Bh1} -> buf1
  stageHT(Bp, &lB[0][0][0][0], 0);
  stageHT(Ap, &lA[0][0][0][0], 0);
  stageHT(Bp, &lB[0][1][0][0], 32);
  stageHT(Ap, &lA[0][1][0][0], 32);
  stageHT(Bp, &lB[1][0][0][0], 64);
  stageHT(Ap, &lA[1][0][0][0], 64);
  stageHT(Bp, &lB[1][1][0][0], 96);
  asm volatile("s_waitcnt vmcnt(6)" ::: "memory");  // T0 fully landed
  __builtin_amdgcn_s_barrier();
  __builtin_amdgcn_sched_barrier(0);

  bf16x8 bfr[4], a[4];

  for (int T = 0; T < nt; ++T) {
    const int bf = T & 1, nb = bf ^ 1;
    const int kc2 = (T + 2) << 6;
    unsigned short (*lAb)[256][32] = lA[bf];
    unsigned short (*lBb)[256][32] = lB[bf];

    // ---- phase 1: B kk0 + A kk0 lo ----
    READ_B4(bf, 0);
    READ_A4(bf, 0, 0);
    if (T + 1 < nt) stageHT(Ap, &lA[nb][1][0][0], ((T + 1) << 6) + 32);
    PHASE_SYNC_PRE();
    MFMA16(0);
    PHASE_SYNC_POST();

    // ---- phase 2: A kk0 hi ----
    READ_A4(bf, 0, 4);
    if (T + 2 < nt) stageHT(Bp, &lBb[0][0][0], kc2);
    PHASE_SYNC_PRE();
    MFMA16(4);
    PHASE_SYNC_POST();

    // ---- phase 3: B kk1 + A kk1 lo ----
    READ_B4(bf, 1);
    READ_A4(bf, 1, 0);
    if (T + 2 < nt) stageHT(Ap, &lAb[0][0][0], kc2);
    PHASE_SYNC_PRE();
    MFMA16(0);
    PHASE_SYNC_POST();

    // ---- phase 4: A kk1 hi ----
    READ_A4(bf, 1, 4);
    if (T + 2 < nt) stageHT(Bp, &lBb[1][0][0], kc2 + 32);
    __builtin_amdgcn_sched_barrier(0);
    __builtin_amdgcn_s_barrier();
    asm volatile("s_waitcnt lgkmcnt(0)" ::: "memory");
    __builtin_amdgcn_sched_barrier(0);
    __builtin_amdgcn_s_setprio(1);
    MFMA16(4);
    __builtin_amdgcn_s_setprio(0);
    __builtin_amdgcn_sched_barrier(0);
    if (T < nt - 2)
      asm volatile("s_waitcnt vmcnt(6)" ::: "memory");   // next tile landed
    else if (T == nt - 2)
      asm volatile("s_waitcnt vmcnt(0)" ::: "memory");   // tail drain
    __builtin_amdgcn_s_barrier();
    __builtin_amdgcn_sched_barrier(0);
  }

#pragma unroll
  for (int mf = 0; mf < 8; ++mf)
#pragma unroll
    for (int nf = 0; nf < 4; ++nf) {
      int row = m0 + wr * 128 + mf * 16 + g * 4;
      int col = n0 + wc * 64 + nf * 16 + lq;
#pragma unroll
      for (int r = 0; r < 4; ++r)
        storeC(C, (size_t)(row + r) * N + col, acc[mf][nf][r]);
    }
}

// ---------------- RoPE on Q in place (+ fold 1/sqrt(HD)) ----------------
__global__ void k_rope_q(unsigned short* __restrict__ qkv,
                         const float* __restrict__ cosT, const float* __restrict__ sinT) {
  int idx = blockIdx.x * blockDim.x + threadIdx.x;
  if (idx >= 2048 * 32 * 64) return;
  int d0 = idx & 63;
  int h = (idx >> 6) & 31;
  int m = idx >> 11;
  int s = m & 1023;
  unsigned short* row = qkv + (size_t)m * 5120 + h * 128;
  float a = bf2f(row[d0]), b = bf2f(row[d0 + 64]);
  float c0 = cosT[s * 128 + d0], s0 = sinT[s * 128 + d0];
  float c1 = cosT[s * 128 + d0 + 64], s1 = sinT[s * 128 + d0 + 64];
  const float sc = 0.08838834764831845f;  // 128^-0.5
  row[d0] = f2bf((a * c0 - b * s0) * sc);
  row[d0 + 64] = f2bf((b * c1 + a * s1) * sc);
}

// ---------------- build K: concat(vision,text) + RoPE, head-major ----------
__global__ void k_build_k(const unsigned short* __restrict__ qkv,   // k = cols 4096..4607
                          const unsigned short* __restrict__ vkv,   // k = cols 0..511
                          const float* __restrict__ cosT, const float* __restrict__ sinT,
                          unsigned short* __restrict__ k_all) {     // [8][1280][128]
  int idx = blockIdx.x * blockDim.x + threadIdx.x;
  if (idx >= 8 * 1280 * 64) return;
  int d0 = idx & 63;
  int t = (idx >> 6) % 1280;
  int bg = idx / (64 * 1280);
  int b = bg >> 2, g = bg & 3;
  float a, bb;
  if (t < 256) {
    const unsigned short* src = vkv + (size_t)(b * 256 + t) * 1024 + g * 128;
    a = bf2f(src[d0]); bb = bf2f(src[d0 + 64]);
  } else {
    const unsigned short* src = qkv + (size_t)(b * 1024 + t - 256) * 5120 + 4096 + g * 128;
    a = bf2f(src[d0]); bb = bf2f(src[d0 + 64]);
  }
  float c0 = cosT[t * 128 + d0], s0 = sinT[t * 128 + d0];
  float c1 = cosT[t * 128 + d0 + 64], s1 = sinT[t * 128 + d0 + 64];
  unsigned short* dst = k_all + ((size_t)bg * 1280 + t) * 128;
  dst[d0] = f2bf(a * c0 - bb * s0);
  dst[d0 + 64] = f2bf(bb * c1 + a * s1);
}

// ---------------- build V transposed: [8][128 d][1280 t] ----------------
__global__ void k_build_v(const unsigned short* __restrict__ qkv,   // v = cols 4608..5119
                          const unsigned short* __restrict__ vkv,   // v = cols 512..1023
                          unsigned short* __restrict__ v_t) {
  int idx = blockIdx.x * blockDim.x + threadIdx.x;
  if (idx >= 8 * 128 * 1280) return;
  int t = idx % 1280;
  int d = (idx / 1280) & 127;
  int bg = idx / (1280 * 128);
  int b = bg >> 2, g = bg & 3;
  unsigned short v;
  if (t < 256) v = vkv[(size_t)(b * 256 + t) * 1024 + 512 + g * 128 + d];
  else         v = qkv[(size_t)(b * 1024 + t - 256) * 5120 + 4608 + g * 128 + d];
  v_t[(size_t)bg * 128 * 1280 + (size_t)d * 1280 + t] = v;
}

// ---------------- flash attention: swapped QK^T + in-register softmax ------
__global__ __launch_bounds__(256) void k_attn(
    const unsigned short* __restrict__ qr,     // [2048][5120] roped, pre-scaled (cols 0..4095)
    const unsigned short* __restrict__ k_all,  // [8][1280][128]
    const unsigned short* __restrict__ v_t,    // [8][128][1280]
    unsigned short* __restrict__ attn) {       // [2048][4096]
  __shared__ __align__(16) unsigned short lK[2][64 * 128];
  __shared__ __align__(16) unsigned short lV[2][128 * 64];
  __shared__ __align__(16) unsigned short lPT[4][16][64];

  const int tid = threadIdx.x, w = tid >> 6, l = tid & 63;
  const int lq = l & 15, g = l >> 4;
  const int qb = (15 - (int)blockIdx.x) * 64;   // longest-running tiles first
  const int h = blockIdx.y, b = blockIdx.z;
  const int bg = b * 4 + (h >> 3);
  const unsigned short* kg = k_all + (size_t)bg * 1280 * 128;
  const unsigned short* vg = v_t + (size_t)bg * 128 * 1280;

  char* lKc = (char*)lK;
  char* lVc = (char*)lV;
  char* pbuf = (char*)&lPT[w][0][0];

  bf16x8 aq[4];
  {
    int row = qb + w * 16 + lq;
    const unsigned short* p = qr + (size_t)(b * 1024 + row) * 5120 + h * 128 + g * 8;
    aq[0] = *(const bf16x8*)(p);
    aq[1] = *(const bf16x8*)(p + 32);
    aq[2] = *(const bf16x8*)(p + 64);
    aq[3] = *(const bf16x8*)(p + 96);
  }

  f32x4 o[8];
#pragma unroll
  for (int i = 0; i < 8; ++i) o[i] = f32x4{0.f, 0.f, 0.f, 0.f};
  float mr = -1e30f;
  float lrp = 0.f;

  const int qrow_l = qb + w * 16 + lq;
  int tlim = qb + 320;
  if (tlim > 1280) tlim = 1280;
  const int nIter = tlim >> 6;

  auto stage = [&](int t0, int bufsel) {
#pragma unroll
    for (int p = 0; p < 4; ++p) {  // K tile [64][128]
      int r = (w * 4 + p) * 4 + (l >> 4);
      int c = (l & 15) ^ (r & 7);
      gload_lds16(kg + (size_t)(t0 + r) * 128 + c * 8,
                  lKc + bufsel * 16384 + (w * 4 + p) * 1024);
    }
#pragma unroll
    for (int p = 0; p < 4; ++p) {  // V tile [128][64]
      int d = (w * 4 + p) * 8 + (l >> 3);
      int c = (l & 7) ^ (d & 7);
      gload_lds16(vg + (size_t)d * 1280 + t0 + c * 8,
                  lVc + bufsel * 16384 + (w * 4 + p) * 1024);
    }
  };

  stage(0, 0);
  __syncthreads();

  int buf = 0;
  for (int it = 0; it < nIter; ++it) {
    const int t0 = it << 6;
    if (it + 1 < nIter) stage(t0 + 64, buf ^ 1);

    const char* kbase = lKc + buf * 16384;
    const char* vbase = lVc + buf * 16384;

    f32x4 sT[4];
#pragma unroll
    for (int sub = 0; sub < 4; ++sub) {
      f32x4 s4 = {0.f, 0.f, 0.f, 0.f};
      int krow = sub * 16 + lq;
      const char* kb = kbase + krow * 256;
#pragma unroll
      for (int kk = 0; kk < 4; ++kk) {
        int slot = (kk * 4 + g) ^ (krow & 7);
        bf16x8 kf = *(const bf16x8*)(kb + slot * 16);
        s4 = __builtin_amdgcn_mfma_f32_16x16x32_bf16(kf, aq[kk], s4, 0, 0, 0);
      }
      sT[sub] = s4;
    }

    if (t0 + 63 > qb + w * 16 + 256) {
#pragma unroll
      for (int sub = 0; sub < 4; ++sub)
#pragma unroll
        for (int r = 0; r < 4; ++r) {
          int t = t0 + sub * 16 + 4 * g + r;
          if (t > qrow_l + 256) sT[sub][r] = -1e30f;
        }
    }

    float pm = fmaxf(fmaxf(fmaxf(sT[0][0], sT[0][1]), fmaxf(sT[0][2], sT[0][3])),
                     fmaxf(fmaxf(sT[1][0], sT[1][1]), fmaxf(sT[1][2], sT[1][3])));
    pm = fmaxf(pm, fmaxf(fmaxf(fmaxf(sT[2][0], sT[2][1]), fmaxf(sT[2][2], sT[2][3])),
                         fmaxf(fmaxf(sT[3][0], sT[3][1]), fmaxf(sT[3][2], sT[3][3]))));
    pm = fmaxf(pm, __shfl_xor(pm, 16));
    pm = fmaxf(pm, __shfl_xor(pm, 32));

    if (!__all(pm <= mr + 8.0f)) {
      float mnew = fmaxf(mr, pm);
      float scl = __expf(mr - mnew);
      mr = mnew;
      lrp *= scl;
      float s0 = __shfl(scl, 4 * g + 0);
      float s1 = __shfl(scl, 4 * g + 1);
      float s2 = __shfl(scl, 4 * g + 2);
      float s3 = __shfl(scl, 4 * g + 3);
#pragma unroll
      for (int cs = 0; cs < 8; ++cs) {
        o[cs][0] *= s0; o[cs][1] *= s1; o[cs][2] *= s2; o[cs][3] *= s3;
      }
    }

#pragma unroll
    for (int sub = 0; sub < 4; ++sub) {
      float p0 = __expf(sT[sub][0] - mr);
      float p1 = __expf(sT[sub][1] - mr);
      float p2 = __expf(sT[sub][2] - mr);
      float p3 = __expf(sT[sub][3] - mr);
      lrp += (p0 + p1) + (p2 + p3);
      unsigned pk0, pk1;
      asm("v_cvt_pk_bf16_f32 %0, %1, %2" : "=v"(pk0) : "v"(p0), "v"(p1));
      asm("v_cvt_pk_bf16_f32 %0, %1, %2" : "=v"(pk1) : "v"(p2), "v"(p3));
      int c = (2 * sub + (g >> 1)) ^ (lq & 7);
      *(uint2*)(pbuf + lq * 128 + c * 16 + (g & 1) * 8) = make_uint2(pk0, pk1);
    }

    asm volatile("s_waitcnt lgkmcnt(0)" ::: "memory");
    __builtin_amdgcn_sched_barrier(0);

    bf16x8 pa0 = *(const bf16x8*)(pbuf + lq * 128 + ((g ^ (lq & 7)) * 16));
    bf16x8 pa1 = *(const bf16x8*)(pbuf + lq * 128 + (((4 + g) ^ (lq & 7)) * 16));

#pragma unroll
    for (int cs = 0; cs < 8; ++cs) {
      int drow = cs * 16 + lq;
      const char* vb = vbase + drow * 128;
      int s0i = g ^ (drow & 7);
      int s1i = (4 + g) ^ (drow & 7);
      bf16x8 v0 = *(const bf16x8*)(vb + s0i * 16);
      bf16x8 v1 = *(const bf16x8*)(vb + s1i * 16);
      o[cs] = __builtin_amdgcn_mfma_f32_16x16x32_bf16(pa0, v0, o[cs], 0, 0, 0);
      o[cs] = __builtin_amdgcn_mfma_f32_16x16x32_bf16(pa1, v1, o[cs], 0, 0, 0);
    }

    __syncthreads();
    buf ^= 1;
  }

  lrp += __shfl_xor(lrp, 16);
  lrp += __shfl_xor(lrp, 32);
  float inv = 1.0f / lrp;
  float invr[4];
  invr[0] = __shfl(inv, 4 * g + 0);
  invr[1] = __shfl(inv, 4 * g + 1);
  invr[2] = __shfl(inv, 4 * g + 2);
  invr[3] = __shfl(inv, 4 * g + 3);
#pragma unroll
  for (int cs = 0; cs < 8; ++cs)
#pragma unroll
    for (int r = 0; r < 4; ++r) {
      int row = qb + w * 16 + 4 * g + r;
      attn[(size_t)(b * 1024 + row) * 4096 + h * 128 + cs * 16 + lq] =
          f2bf(o[cs][r] * invr[r]);
    }
}

// ---------------- launcher ----------------
extern "C" void kernel_launch(void* const* d_in, const int* in_sizes, int n_in,
                              void* d_out, int out_size, void* d_ws, size_t ws_size,
                              hipStream_t stream) {
  const float* x    = (const float*)d_in[0];
  const float* vis  = (const float*)d_in[1];
  const float* wq   = (const float*)d_in[2];
  const float* wk   = (const float*)d_in[3];
  const float* wv   = (const float*)d_in[4];
  const float* wo   = (const float*)d_in[5];
  const float* wvkv = (const float*)d_in[6];
  const float* cosT = (const float*)d_in[7];
  const float* sinT = (const float*)d_in[8];
  float* out = (float*)d_out;
  char* ws = (char*)d_ws;

  size_t off = 0;
  auto alloc = [&](size_t b) { size_t r = off; off += (b + 255) & ~(size_t)255; return r; };
  unsigned short* wqkvb = (unsigned short*)(ws + alloc((size_t)5120 * 4096 * 2));  // wq|wk|wv
  unsigned short* wob   = (unsigned short*)(ws + alloc((size_t)4096 * 4096 * 2));
  unsigned short* wvkvb = (unsigned short*)(ws + alloc((size_t)1024 * 768 * 2));
  unsigned short* visb  = (unsigned short*)(ws + alloc((size_t)512 * 768 * 2));
  unsigned short* xb    = (unsigned short*)(ws + alloc((size_t)2048 * 4096 * 2));
  unsigned short* qkv   = (unsigned short*)(ws + alloc((size_t)2048 * 5120 * 2));
  unsigned short* vkvb  = (unsigned short*)(ws + alloc((size_t)512 * 1024 * 2));
  unsigned short* kall  = (unsigned short*)(ws + alloc((size_t)8 * 1280 * 128 * 2));
  unsigned short* vt    = (unsigned short*)(ws + alloc((size_t)8 * 128 * 1280 * 2));
  unsigned short* attnb = xb;  // x is dead after the QKV projection; reuse
  if (ws_size < off) return;

  auto cast = [&](const float* src, unsigned short* dst, size_t n) {
    int n4 = (int)(n / 4);
    int grid = (n4 + 255) / 256;
    if (grid > 1280) grid = 1280;
    k_cast<<<dim3(grid), dim3(256), 0, stream>>>(src, dst, n4);
  };
  cast(x, xb, (size_t)2048 * 4096);
  cast(wq, wqkvb, (size_t)4096 * 4096);
  cast(wk, wqkvb + (size_t)4096 * 4096, (size_t)512 * 4096);
  cast(wv, wqkvb + (size_t)4608 * 4096, (size_t)512 * 4096);
  cast(wo, wob, (size_t)4096 * 4096);
  cast(wvkv, wvkvb, (size_t)1024 * 768);
  cast(vis, visb, (size_t)512 * 768);

  // fused QKV projection: [2048][5120] — 256² 8-phase, grid 8*(5120/256)=160
  k_gemm256<unsigned short><<<dim3(160), dim3(512), 0, stream>>>(xb, wqkvb, qkv, 2048, 5120, 4096);
  k_gemm_bt<unsigned short><<<dim3(4, 8), dim3(256), 0, stream>>>(visb, wvkvb, vkvb, 512, 1024, 768);

  k_rope_q<<<dim3(16384), dim3(256), 0, stream>>>(qkv, cosT, sinT);
  k_build_k<<<dim3(2560), dim3(256), 0, stream>>>(qkv, vkvb, cosT, sinT, kall);
  k_build_v<<<dim3(5120), dim3(256), 0, stream>>>(qkv, vkvb, vt);

  k_attn<<<dim3(16, 32, 2), dim3(256), 0, stream>>>(qkv, kall, vt, attnb);

  // out projection — 256² 8-phase, grid 8*(4096/256)=128
  k_gemm256<float><<<dim3(128), dim3(512), 0, stream>>>(attnb, wob, out, 2048, 4096, 4096);
}

// Round 6
// 353.810 us; speedup vs baseline: 1.1395x; 1.1395x over previous
//
#include <hip/hip_runtime.h>
#include <hip/hip_bf16.h>
#include <cstdint>
#include <cstddef>

typedef short bf16x8 __attribute__((ext_vector_type(8)));
typedef float f32x4 __attribute__((ext_vector_type(4)));

__device__ __forceinline__ void gload_lds16(const void* g, void* l) {
  __builtin_amdgcn_global_load_lds((__attribute__((address_space(1))) const void*)g,
                                   (__attribute__((address_space(3))) void*)l, 16, 0, 0);
}

__device__ __forceinline__ unsigned short f2bf(float f) {
  unsigned u = __builtin_bit_cast(unsigned, f);
  u += 0x7fffu + ((u >> 16) & 1u);
  return (unsigned short)(u >> 16);
}
__device__ __forceinline__ float bf2f(unsigned short h) {
  unsigned u = ((unsigned)h) << 16;
  return __builtin_bit_cast(float, u);
}

// ---------------- all casts f32 -> bf16 in one launch ----------------
struct CastPack {
  const float* s[7];
  unsigned short* d[7];
  int n4[7];
};
__global__ void k_cast_all(CastPack p) {
  const int tid0 = blockIdx.x * blockDim.x + threadIdx.x;
  const int stride = gridDim.x * blockDim.x;
#pragma unroll 1
  for (int seg = 0; seg < 7; ++seg) {
    const float4* __restrict__ src = reinterpret_cast<const float4*>(p.s[seg]);
    ushort4* __restrict__ dst = reinterpret_cast<ushort4*>(p.d[seg]);
    const int n4 = p.n4[seg];
    for (int i = tid0; i < n4; i += stride) {
      float4 v = src[i];
      ushort4 o;
      o.x = f2bf(v.x); o.y = f2bf(v.y); o.z = f2bf(v.z); o.w = f2bf(v.w);
      dst[i] = o;
    }
  }
}

__device__ __forceinline__ void storeC(float* C, size_t i, float v) { C[i] = v; }
__device__ __forceinline__ void storeC(unsigned short* C, size_t i, float v) { C[i] = f2bf(v); }

// ---------------- 128x128 GEMM (m97 structure) -----------------------------
template <typename OutT>
__global__ __launch_bounds__(256) void k_gemm_bt(
    const unsigned short* __restrict__ A,
    const unsigned short* __restrict__ B,
    OutT* __restrict__ C,
    int M, int N, int K) {
  __shared__ __align__(16) unsigned short lA[128 * 64];
  __shared__ __align__(16) unsigned short lB[128 * 64];
  const int tid = threadIdx.x;
  const int w = tid >> 6, l = tid & 63;
  const int nwg = gridDim.x * gridDim.y;
  const int orig = blockIdx.y * gridDim.x + blockIdx.x;
  const int cpx = nwg >> 3;
  const int tile = (orig & 7) * cpx + (orig >> 3);
  const int m0 = (tile % gridDim.x) * 128;
  const int n0 = (tile / gridDim.x) * 128;
  const int wm = (w >> 1) * 64, wn = (w & 1) * 64;

  f32x4 acc[4][4];
#pragma unroll
  for (int i = 0; i < 4; ++i)
#pragma unroll
    for (int j = 0; j < 4; ++j) acc[i][j] = f32x4{0.f, 0.f, 0.f, 0.f};

  char* lAc = (char*)lA;
  char* lBc = (char*)lB;

  for (int k0 = 0; k0 < K; k0 += 64) {
#pragma unroll
    for (int p = 0; p < 4; ++p) {
      int r = (w * 4 + p) * 8 + (l >> 3);
      int c = (l & 7) ^ (r & 7);
      gload_lds16(A + (size_t)(m0 + r) * K + k0 + c * 8, lAc + (w * 4 + p) * 1024);
      gload_lds16(B + (size_t)(n0 + r) * K + k0 + c * 8, lBc + (w * 4 + p) * 1024);
    }
    __syncthreads();
#pragma unroll
    for (int kk = 0; kk < 2; ++kk) {
      bf16x8 af[4], bfr[4];
#pragma unroll
      for (int i = 0; i < 4; ++i) {
        int r = wm + i * 16 + (l & 15);
        int slot = (kk * 4 + (l >> 4)) ^ (r & 7);
        af[i] = *(const bf16x8*)(lAc + r * 128 + slot * 16);
      }
#pragma unroll
      for (int j = 0; j < 4; ++j) {
        int r = wn + j * 16 + (l & 15);
        int slot = (kk * 4 + (l >> 4)) ^ (r & 7);
        bfr[j] = *(const bf16x8*)(lBc + r * 128 + slot * 16);
      }
#pragma unroll
      for (int i = 0; i < 4; ++i)
#pragma unroll
        for (int j = 0; j < 4; ++j)
          acc[i][j] = __builtin_amdgcn_mfma_f32_16x16x32_bf16(af[i], bfr[j], acc[i][j], 0, 0, 0);
    }
    __syncthreads();
  }

#pragma unroll
  for (int i = 0; i < 4; ++i)
#pragma unroll
    for (int j = 0; j < 4; ++j) {
      int row = m0 + wm + i * 16 + (l >> 4) * 4;
      int col = n0 + wn + j * 16 + (l & 15);
#pragma unroll
      for (int r = 0; r < 4; ++r)
        storeC(C, (size_t)(row + r) * N + col, acc[i][j][r]);
    }
}

// ---------------- 256x128 pipelined GEMM — full-GPU grid -------------------
// Grid = (M/256)*(N/128) blocks (out-proj: 8*32 = 256 = 1/CU on every CU).
// 512 thr (8 waves, 2m x 4n; wave tile 128x32). LDS 96KB:
//   lA[2 buf][2 kk-half][256][32], lB[2][2][128][32], XOR chunk swizzle.
// 2 phases per K-tile, 16 MFMA each. Stage plan (liveness-verified):
//   p1: read B[bf][0]+A[bf][0]; stage (T+1)h1 -> A[nb][1],B[nb][1] (dead since T-1 p2)
//   p2: read B[bf][1]+A[bf][1]; stage (T+2)h0 -> A[bf][0],B[bf][0] (dead after p1 barrier)
// End-of-tile vmcnt(3): waits p1's stages (T+1 complete), leaves p2's 3 loads
// (T+2 pieces) in flight across the whole next tile.
#define PHASE_SYNC_PRE()                         \
  __builtin_amdgcn_sched_barrier(0);             \
  __builtin_amdgcn_s_barrier();                  \
  asm volatile("s_waitcnt lgkmcnt(0)" ::: "memory"); \
  __builtin_amdgcn_sched_barrier(0);             \
  __builtin_amdgcn_s_setprio(1);
#define PHASE_SYNC_POST()                        \
  __builtin_amdgcn_s_setprio(0);                 \
  __builtin_amdgcn_sched_barrier(0);             \
  __builtin_amdgcn_s_barrier();                  \
  __builtin_amdgcn_sched_barrier(0);
#define XREAD_B2(bf, kh)                                                     \
  bfr[0] = *(const bf16x8*)&lB[bf][kh][wc * 32 + 0 + lq][fslot];             \
  bfr[1] = *(const bf16x8*)&lB[bf][kh][wc * 32 + 16 + lq][fslot];
#define XREAD_A8(bf, kh)                                                     \
  _Pragma("unroll") for (int mf = 0; mf < 8; ++mf)                           \
      a[mf] = *(const bf16x8*)&lA[bf][kh][wr * 128 + mf * 16 + lq][fslot];
#define XMFMA16()                                                            \
  _Pragma("unroll") for (int mf = 0; mf < 8; ++mf)                           \
      _Pragma("unroll") for (int nf = 0; nf < 2; ++nf)                       \
          acc[mf][nf] = __builtin_amdgcn_mfma_f32_16x16x32_bf16(             \
              a[mf], bfr[nf], acc[mf][nf], 0, 0, 0);

template <typename OutT>
__global__ __launch_bounds__(512) void k_gemm256x128(
    const unsigned short* __restrict__ A,
    const unsigned short* __restrict__ B,
    OutT* __restrict__ C,
    int M, int N, int K) {
  __shared__ __align__(16) unsigned short lA[2][2][256][32];
  __shared__ __align__(16) unsigned short lB[2][2][128][32];
  const int tid = threadIdx.x;
  const int w = tid >> 6, l = tid & 63;
  const int wr = w >> 2, wc = w & 3;
  const int lq = l & 15, g = l >> 4;
  const int fslot = (g ^ ((lq >> 1) & 3)) << 3;

  // XCD partition: each XCD owns a contiguous N-strip (B panel L2-resident).
  const int gm = M >> 8, gn = N >> 7;
  const int L = (int)blockIdx.x;
  const int xcd = L & 7, slot = L >> 3;
  const int m0 = (slot % gm) * 256;
  const int n0 = (xcd * (gn >> 3) + slot / gm) * 128;

  const unsigned short* Ap = A + (size_t)m0 * K;
  const unsigned short* Bp = B + (size_t)n0 * K;

  f32x4 acc[8][2];
#pragma unroll
  for (int i = 0; i < 8; ++i)
#pragma unroll
    for (int j = 0; j < 2; ++j) acc[i][j] = f32x4{0.f, 0.f, 0.f, 0.f};

  auto stageA = [&](unsigned short* lbase, int kcol) {  // [256][32] half: 2 gloads
#pragma unroll
    for (int p = 0; p < 2; ++p) {
      int R = w * 32 + p * 16;
      int row = R + (l >> 2);
      int cc = ((l & 3) ^ ((l >> 3) & 3)) << 3;
      gload_lds16(Ap + (size_t)row * K + kcol + cc, lbase + R * 32);
    }
  };
  auto stageB = [&](unsigned short* lbase, int kcol) {  // [128][32] half: 1 gload
    int R = w * 16;
    int row = R + (l >> 2);
    int cc = ((l & 3) ^ ((l >> 3) & 3)) << 3;
    gload_lds16(Bp + (size_t)row * K + kcol + cc, lbase + R * 32);
  };

  const int nt = K >> 6;

  // prologue: T0 complete (6 loads), T1 h0 pieces (3 loads)
  stageB(&lB[0][0][0][0], 0);
  stageA(&lA[0][0][0][0], 0);
  stageB(&lB[0][1][0][0], 32);
  stageA(&lA[0][1][0][0], 32);
  stageB(&lB[1][0][0][0], 64);
  stageA(&lA[1][0][0][0], 64);
  asm volatile("s_waitcnt vmcnt(3)" ::: "memory");  // T0 landed
  __builtin_amdgcn_s_barrier();
  __builtin_amdgcn_sched_barrier(0);

  bf16x8 bfr[2], a[8];

  for (int T = 0; T < nt; ++T) {
    const int bf = T & 1, nb = bf ^ 1;

    // ---- phase 1: kk0 ----
    XREAD_B2(bf, 0);
    XREAD_A8(bf, 0);
    if (T + 1 < nt) {
      stageA(&lA[nb][1][0][0], ((T + 1) << 6) + 32);
      stageB(&lB[nb][1][0][0], ((T + 1) << 6) + 32);
    }
    PHASE_SYNC_PRE();
    XMFMA16();
    PHASE_SYNC_POST();

    // ---- phase 2: kk1 ----
    XREAD_B2(bf, 1);
    XREAD_A8(bf, 1);
    if (T + 2 < nt) {
      stageA(&lA[bf][0][0][0], (T + 2) << 6);
      stageB(&lB[bf][0][0][0], (T + 2) << 6);
    }
    PHASE_SYNC_PRE();
    XMFMA16();
    __builtin_amdgcn_s_setprio(0);
    __builtin_amdgcn_sched_barrier(0);
    if (T < nt - 2)
      asm volatile("s_waitcnt vmcnt(3)" ::: "memory");   // (T+1) pieces landed
    else if (T == nt - 2)
      asm volatile("s_waitcnt vmcnt(0)" ::: "memory");   // tail drain
    __builtin_amdgcn_s_barrier();
    __builtin_amdgcn_sched_barrier(0);
  }

#pragma unroll
  for (int mf = 0; mf < 8; ++mf)
#pragma unroll
    for (int nf = 0; nf < 2; ++nf) {
      int row = m0 + wr * 128 + mf * 16 + g * 4;
      int col = n0 + wc * 32 + nf * 16 + lq;
#pragma unroll
      for (int r = 0; r < 4; ++r)
        storeC(C, (size_t)(row + r) * N + col, acc[mf][nf][r]);
    }
}

// ---------------- RoPE on Q in place (+ fold 1/sqrt(HD)) ----------------
__global__ void k_rope_q(unsigned short* __restrict__ qkv,
                         const float* __restrict__ cosT, const float* __restrict__ sinT) {
  int idx = blockIdx.x * blockDim.x + threadIdx.x;
  if (idx >= 2048 * 32 * 64) return;
  int d0 = idx & 63;
  int h = (idx >> 6) & 31;
  int m = idx >> 11;
  int s = m & 1023;
  unsigned short* row = qkv + (size_t)m * 5120 + h * 128;
  float a = bf2f(row[d0]), b = bf2f(row[d0 + 64]);
  float c0 = cosT[s * 128 + d0], s0 = sinT[s * 128 + d0];
  float c1 = cosT[s * 128 + d0 + 64], s1 = sinT[s * 128 + d0 + 64];
  const float sc = 0.08838834764831845f;  // 128^-0.5
  row[d0] = f2bf((a * c0 - b * s0) * sc);
  row[d0 + 64] = f2bf((b * c1 + a * s1) * sc);
}

// ---------------- build K: concat(vision,text) + RoPE, head-major ----------
__global__ void k_build_k(const unsigned short* __restrict__ qkv,   // k = cols 4096..4607
                          const unsigned short* __restrict__ vkv,   // k = cols 0..511
                          const float* __restrict__ cosT, const float* __restrict__ sinT,
                          unsigned short* __restrict__ k_all) {     // [8][1280][128]
  int idx = blockIdx.x * blockDim.x + threadIdx.x;
  if (idx >= 8 * 1280 * 64) return;
  int d0 = idx & 63;
  int t = (idx >> 6) % 1280;
  int bg = idx / (64 * 1280);
  int b = bg >> 2, g = bg & 3;
  float a, bb;
  if (t < 256) {
    const unsigned short* src = vkv + (size_t)(b * 256 + t) * 1024 + g * 128;
    a = bf2f(src[d0]); bb = bf2f(src[d0 + 64]);
  } else {
    const unsigned short* src = qkv + (size_t)(b * 1024 + t - 256) * 5120 + 4096 + g * 128;
    a = bf2f(src[d0]); bb = bf2f(src[d0 + 64]);
  }
  float c0 = cosT[t * 128 + d0], s0 = sinT[t * 128 + d0];
  float c1 = cosT[t * 128 + d0 + 64], s1 = sinT[t * 128 + d0 + 64];
  unsigned short* dst = k_all + ((size_t)bg * 1280 + t) * 128;
  dst[d0] = f2bf(a * c0 - bb * s0);
  dst[d0 + 64] = f2bf(bb * c1 + a * s1);
}

// ---------------- build V transposed: [8][128 d][1280 t] ----------------
__global__ void k_build_v(const unsigned short* __restrict__ qkv,   // v = cols 4608..5119
                          const unsigned short* __restrict__ vkv,   // v = cols 512..1023
                          unsigned short* __restrict__ v_t) {
  int idx = blockIdx.x * blockDim.x + threadIdx.x;
  if (idx >= 8 * 128 * 1280) return;
  int t = idx % 1280;
  int d = (idx / 1280) & 127;
  int bg = idx / (1280 * 128);
  int b = bg >> 2, g = bg & 3;
  unsigned short v;
  if (t < 256) v = vkv[(size_t)(b * 256 + t) * 1024 + 512 + g * 128 + d];
  else         v = qkv[(size_t)(b * 1024 + t - 256) * 5120 + 4608 + g * 128 + d];
  v_t[(size_t)bg * 128 * 1280 + (size_t)d * 1280 + t] = v;
}

// ---------------- flash attention: swapped QK^T + in-register softmax ------
__global__ __launch_bounds__(256) void k_attn(
    const unsigned short* __restrict__ qr,     // [2048][5120] roped, pre-scaled (cols 0..4095)
    const unsigned short* __restrict__ k_all,  // [8][1280][128]
    const unsigned short* __restrict__ v_t,    // [8][128][1280]
    unsigned short* __restrict__ attn) {       // [2048][4096]
  __shared__ __align__(16) unsigned short lK[2][64 * 128];
  __shared__ __align__(16) unsigned short lV[2][128 * 64];
  __shared__ __align__(16) unsigned short lPT[4][16][64];

  const int tid = threadIdx.x, w = tid >> 6, l = tid & 63;
  const int lq = l & 15, g = l >> 4;
  const int qb = (15 - (int)blockIdx.x) * 64;   // longest-running tiles first
  const int h = blockIdx.y, b = blockIdx.z;
  const int bg = b * 4 + (h >> 3);
  const unsigned short* kg = k_all + (size_t)bg * 1280 * 128;
  const unsigned short* vg = v_t + (size_t)bg * 128 * 1280;

  char* lKc = (char*)lK;
  char* lVc = (char*)lV;
  char* pbuf = (char*)&lPT[w][0][0];

  bf16x8 aq[4];
  {
    int row = qb + w * 16 + lq;
    const unsigned short* p = qr + (size_t)(b * 1024 + row) * 5120 + h * 128 + g * 8;
    aq[0] = *(const bf16x8*)(p);
    aq[1] = *(const bf16x8*)(p + 32);
    aq[2] = *(const bf16x8*)(p + 64);
    aq[3] = *(const bf16x8*)(p + 96);
  }

  f32x4 o[8];
#pragma unroll
  for (int i = 0; i < 8; ++i) o[i] = f32x4{0.f, 0.f, 0.f, 0.f};
  float mr = -1e30f;
  float lrp = 0.f;

  const int qrow_l = qb + w * 16 + lq;
  int tlim = qb + 320;
  if (tlim > 1280) tlim = 1280;
  const int nIter = tlim >> 6;

  auto stage = [&](int t0, int bufsel) {
#pragma unroll
    for (int p = 0; p < 4; ++p) {  // K tile [64][128]
      int r = (w * 4 + p) * 4 + (l >> 4);
      int c = (l & 15) ^ (r & 7);
      gload_lds16(kg + (size_t)(t0 + r) * 128 + c * 8,
                  lKc + bufsel * 16384 + (w * 4 + p) * 1024);
    }
#pragma unroll
    for (int p = 0; p < 4; ++p) {  // V tile [128][64]
      int d = (w * 4 + p) * 8 + (l >> 3);
      int c = (l & 7) ^ (d & 7);
      gload_lds16(vg + (size_t)d * 1280 + t0 + c * 8,
                  lVc + bufsel * 16384 + (w * 4 + p) * 1024);
    }
  };

  stage(0, 0);
  __syncthreads();

  int buf = 0;
  for (int it = 0; it < nIter; ++it) {
    const int t0 = it << 6;
    if (it + 1 < nIter) stage(t0 + 64, buf ^ 1);

    const char* kbase = lKc + buf * 16384;
    const char* vbase = lVc + buf * 16384;

    f32x4 sT[4];
#pragma unroll
    for (int sub = 0; sub < 4; ++sub) {
      f32x4 s4 = {0.f, 0.f, 0.f, 0.f};
      int krow = sub * 16 + lq;
      const char* kb = kbase + krow * 256;
#pragma unroll
      for (int kk = 0; kk < 4; ++kk) {
        int slot = (kk * 4 + g) ^ (krow & 7);
        bf16x8 kf = *(const bf16x8*)(kb + slot * 16);
        s4 = __builtin_amdgcn_mfma_f32_16x16x32_bf16(kf, aq[kk], s4, 0, 0, 0);
      }
      sT[sub] = s4;
    }

    if (t0 + 63 > qb + w * 16 + 256) {
#pragma unroll
      for (int sub = 0; sub < 4; ++sub)
#pragma unroll
        for (int r = 0; r < 4; ++r) {
          int t = t0 + sub * 16 + 4 * g + r;
          if (t > qrow_l + 256) sT[sub][r] = -1e30f;
        }
    }

    float pm = fmaxf(fmaxf(fmaxf(sT[0][0], sT[0][1]), fmaxf(sT[0][2], sT[0][3])),
                     fmaxf(fmaxf(sT[1][0], sT[1][1]), fmaxf(sT[1][2], sT[1][3])));
    pm = fmaxf(pm, fmaxf(fmaxf(fmaxf(sT[2][0], sT[2][1]), fmaxf(sT[2][2], sT[2][3])),
                         fmaxf(fmaxf(sT[3][0], sT[3][1]), fmaxf(sT[3][2], sT[3][3]))));
    pm = fmaxf(pm, __shfl_xor(pm, 16));
    pm = fmaxf(pm, __shfl_xor(pm, 32));

    if (!__all(pm <= mr + 8.0f)) {
      float mnew = fmaxf(mr, pm);
      float scl = __expf(mr - mnew);
      mr = mnew;
      lrp *= scl;
      float s0 = __shfl(scl, 4 * g + 0);
      float s1 = __shfl(scl, 4 * g + 1);
      float s2 = __shfl(scl, 4 * g + 2);
      float s3 = __shfl(scl, 4 * g + 3);
#pragma unroll
      for (int cs = 0; cs < 8; ++cs) {
        o[cs][0] *= s0; o[cs][1] *= s1; o[cs][2] *= s2; o[cs][3] *= s3;
      }
    }

#pragma unroll
    for (int sub = 0; sub < 4; ++sub) {
      float p0 = __expf(sT[sub][0] - mr);
      float p1 = __expf(sT[sub][1] - mr);
      float p2 = __expf(sT[sub][2] - mr);
      float p3 = __expf(sT[sub][3] - mr);
      lrp += (p0 + p1) + (p2 + p3);
      unsigned pk0, pk1;
      asm("v_cvt_pk_bf16_f32 %0, %1, %2" : "=v"(pk0) : "v"(p0), "v"(p1));
      asm("v_cvt_pk_bf16_f32 %0, %1, %2" : "=v"(pk1) : "v"(p2), "v"(p3));
      int c = (2 * sub + (g >> 1)) ^ (lq & 7);
      *(uint2*)(pbuf + lq * 128 + c * 16 + (g & 1) * 8) = make_uint2(pk0, pk1);
    }

    asm volatile("s_waitcnt lgkmcnt(0)" ::: "memory");
    __builtin_amdgcn_sched_barrier(0);

    bf16x8 pa0 = *(const bf16x8*)(pbuf + lq * 128 + ((g ^ (lq & 7)) * 16));
    bf16x8 pa1 = *(const bf16x8*)(pbuf + lq * 128 + (((4 + g) ^ (lq & 7)) * 16));

#pragma unroll
    for (int cs = 0; cs < 8; ++cs) {
      int drow = cs * 16 + lq;
      const char* vb = vbase + drow * 128;
      int s0i = g ^ (drow & 7);
      int s1i = (4 + g) ^ (drow & 7);
      bf16x8 v0 = *(const bf16x8*)(vb + s0i * 16);
      bf16x8 v1 = *(const bf16x8*)(vb + s1i * 16);
      o[cs] = __builtin_amdgcn_mfma_f32_16x16x32_bf16(pa0, v0, o[cs], 0, 0, 0);
      o[cs] = __builtin_amdgcn_mfma_f32_16x16x32_bf16(pa1, v1, o[cs], 0, 0, 0);
    }

    __syncthreads();
    buf ^= 1;
  }

  lrp += __shfl_xor(lrp, 16);
  lrp += __shfl_xor(lrp, 32);
  float inv = 1.0f / lrp;
  float invr[4];
  invr[0] = __shfl(inv, 4 * g + 0);
  invr[1] = __shfl(inv, 4 * g + 1);
  invr[2] = __shfl(inv, 4 * g + 2);
  invr[3] = __shfl(inv, 4 * g + 3);
#pragma unroll
  for (int cs = 0; cs < 8; ++cs)
#pragma unroll
    for (int r = 0; r < 4; ++r) {
      int row = qb + w * 16 + 4 * g + r;
      attn[(size_t)(b * 1024 + row) * 4096 + h * 128 + cs * 16 + lq] =
          f2bf(o[cs][r] * invr[r]);
    }
}

// ---------------- launcher ----------------
extern "C" void kernel_launch(void* const* d_in, const int* in_sizes, int n_in,
                              void* d_out, int out_size, void* d_ws, size_t ws_size,
                              hipStream_t stream) {
  const float* x    = (const float*)d_in[0];
  const float* vis  = (const float*)d_in[1];
  const float* wq   = (const float*)d_in[2];
  const float* wk   = (const float*)d_in[3];
  const float* wv   = (const float*)d_in[4];
  const float* wo   = (const float*)d_in[5];
  const float* wvkv = (const float*)d_in[6];
  const float* cosT = (const float*)d_in[7];
  const float* sinT = (const float*)d_in[8];
  float* out = (float*)d_out;
  char* ws = (char*)d_ws;

  size_t off = 0;
  auto alloc = [&](size_t b) { size_t r = off; off += (b + 255) & ~(size_t)255; return r; };
  unsigned short* wqkvb = (unsigned short*)(ws + alloc((size_t)5120 * 4096 * 2));  // wq|wk|wv
  unsigned short* wob   = (unsigned short*)(ws + alloc((size_t)4096 * 4096 * 2));
  unsigned short* wvkvb = (unsigned short*)(ws + alloc((size_t)1024 * 768 * 2));
  unsigned short* visb  = (unsigned short*)(ws + alloc((size_t)512 * 768 * 2));
  unsigned short* xb    = (unsigned short*)(ws + alloc((size_t)2048 * 4096 * 2));
  unsigned short* qkv   = (unsigned short*)(ws + alloc((size_t)2048 * 5120 * 2));
  unsigned short* vkvb  = (unsigned short*)(ws + alloc((size_t)512 * 1024 * 2));
  unsigned short* kall  = (unsigned short*)(ws + alloc((size_t)8 * 1280 * 128 * 2));
  unsigned short* vt    = (unsigned short*)(ws + alloc((size_t)8 * 128 * 1280 * 2));
  unsigned short* attnb = xb;  // x is dead after the QKV projection; reuse
  if (ws_size < off) return;

  CastPack cp;
  cp.s[0] = x;    cp.d[0] = xb;                           cp.n4[0] = 2048 * 4096 / 4;
  cp.s[1] = wq;   cp.d[1] = wqkvb;                        cp.n4[1] = 4096 * 4096 / 4;
  cp.s[2] = wk;   cp.d[2] = wqkvb + (size_t)4096 * 4096;  cp.n4[2] = 512 * 4096 / 4;
  cp.s[3] = wv;   cp.d[3] = wqkvb + (size_t)4608 * 4096;  cp.n4[3] = 512 * 4096 / 4;
  cp.s[4] = wo;   cp.d[4] = wob;                          cp.n4[4] = 4096 * 4096 / 4;
  cp.s[5] = wvkv; cp.d[5] = wvkvb;                        cp.n4[5] = 1024 * 768 / 4;
  cp.s[6] = vis;  cp.d[6] = visb;                         cp.n4[6] = 512 * 768 / 4;
  k_cast_all<<<dim3(2048), dim3(256), 0, stream>>>(cp);

  // fused QKV projection: [2048][5120] — 128² m97 structure, 640 blocks
  k_gemm_bt<unsigned short><<<dim3(16, 40), dim3(256), 0, stream>>>(xb, wqkvb, qkv, 2048, 5120, 4096);
  k_gemm_bt<unsigned short><<<dim3(4, 8), dim3(256), 0, stream>>>(visb, wvkvb, vkvb, 512, 1024, 768);

  k_rope_q<<<dim3(16384), dim3(256), 0, stream>>>(qkv, cosT, sinT);
  k_build_k<<<dim3(2560), dim3(256), 0, stream>>>(qkv, vkvb, cosT, sinT, kall);
  k_build_v<<<dim3(5120), dim3(256), 0, stream>>>(qkv, vkvb, vt);

  k_attn<<<dim3(16, 32, 2), dim3(256), 0, stream>>>(qkv, kall, vt, attnb);

  // out projection — 256x128 pipelined, grid (2048/256)*(4096/128) = 256
  k_gemm256x128<float><<<dim3(256), dim3(512), 0, stream>>>(attnb, wob, out, 2048, 4096, 4096);
}